// Round 1
// baseline (203.195 us; speedup 1.0000x reference)
//
#include <hip/hip_runtime.h>
#include <math.h>

#define N 4096
#define E 96
#define H 6
#define DH 16
#define G 64
#define QKV (3*E)

// ---------------- K1: qkv = feats @ w_in.T + b_in, split into Q(scaled)/K/V [H][N][DH]
__global__ __launch_bounds__(256) void qkv_kernel(const float* __restrict__ feats,
                                                  const float* __restrict__ w_in,
                                                  const float* __restrict__ b_in,
                                                  float* __restrict__ Qd,
                                                  float* __restrict__ Kd,
                                                  float* __restrict__ Vd) {
    int idx = blockIdx.x * blockDim.x + threadIdx.x;
    if (idx >= N * QKV) return;
    int o = idx % QKV;          // output column in [0,288)
    int i = idx / QKV;          // row
    const float* fr = feats + i * E;
    const float* wr = w_in + o * E;
    float s = 0.f;
    #pragma unroll
    for (int e = 0; e < E; e += 4) {
        float4 f = *(const float4*)(fr + e);
        float4 w = *(const float4*)(wr + e);
        s += f.x*w.x + f.y*w.y + f.z*w.z + f.w*w.w;
    }
    s += b_in[o];
    int part = o / E;           // 0=q 1=k 2=v
    int rem  = o % E;
    int h = rem / DH, d = rem % DH;
    int di = h * N * DH + i * DH + d;
    if      (part == 0) Qd[di] = s * 0.25f;   // 1/sqrt(DH), DH=16
    else if (part == 1) Kd[di] = s;
    else                Vd[di] = s;
}

// ---------------- K2: group histogram
__global__ void hist_kernel(const int* __restrict__ grp, int* __restrict__ counts) {
    int i = blockIdx.x * blockDim.x + threadIdx.x;
    if (i < N) atomicAdd(&counts[grp[i]], 1);
}

// ---------------- K3: exclusive scan over 64 groups (tiny, serial)
__global__ void scan_kernel(const int* __restrict__ counts,
                            int* __restrict__ offs, int* __restrict__ cursor) {
    if (threadIdx.x == 0 && blockIdx.x == 0) {
        int run = 0;
        for (int g = 0; g < G; ++g) { offs[g] = run; cursor[g] = run; run += counts[g]; }
    }
}

// ---------------- K4: scatter row indices into group buckets
__global__ void scatter_kernel(const int* __restrict__ grp,
                               int* __restrict__ cursor, int* __restrict__ bucket) {
    int i = blockIdx.x * blockDim.x + threadIdx.x;
    if (i < N) { int p = atomicAdd(&cursor[grp[i]], 1); bucket[p] = i; }
}

// ---------------- K5: per-(row,head) attention over the row's group bucket
__global__ __launch_bounds__(256) void attn_kernel(const float* __restrict__ Qd,
                                                   const float* __restrict__ Kd,
                                                   const float* __restrict__ Vd,
                                                   const int* __restrict__ grp,
                                                   const int* __restrict__ offs,
                                                   const int* __restrict__ counts,
                                                   const int* __restrict__ bucket,
                                                   float* __restrict__ attn_out) {
    int tid  = blockIdx.x * blockDim.x + threadIdx.x;
    int wid  = tid >> 6;        // one wave per (row, head)
    int lane = threadIdx.x & 63;
    if (wid >= N * H) return;
    int i = wid & (N - 1);      // N = 4096 pow2
    int h = wid >> 12;          // wid / N
    int g = grp[i];
    int off = offs[g], cnt = counts[g];

    const float* qr = Qd + (h * N + i) * DH;
    float ql[DH];
    #pragma unroll
    for (int d = 0; d < DH; ++d) ql[d] = qr[d];

    float m = -INFINITY, l = 0.f;
    float acc[DH];
    #pragma unroll
    for (int d = 0; d < DH; ++d) acc[d] = 0.f;

    for (int mm = lane; mm < cnt; mm += 64) {
        int j = bucket[off + mm];
        const float* kr = Kd + (h * N + j) * DH;
        float s = 0.f;
        #pragma unroll
        for (int d = 0; d < DH; ++d) s += ql[d] * kr[d];
        float nm = fmaxf(m, s);
        float c = __expf(m - nm);   // exp(-inf)=0 on first hit
        float p = __expf(s - nm);
        l = l * c + p;
        const float* vr = Vd + (h * N + j) * DH;
        #pragma unroll
        for (int d = 0; d < DH; ++d) acc[d] = acc[d] * c + p * vr[d];
        m = nm;
    }

    // wave-level online-softmax combine (64-lane butterfly)
    float M = m;
    #pragma unroll
    for (int o = 32; o >= 1; o >>= 1) M = fmaxf(M, __shfl_xor(M, o, 64));
    float scale = (m == -INFINITY) ? 0.f : __expf(m - M);
    float ls = l * scale;
    #pragma unroll
    for (int o = 32; o >= 1; o >>= 1) ls += __shfl_xor(ls, o, 64);
    #pragma unroll
    for (int d = 0; d < DH; ++d) {
        float a = acc[d] * scale;
        #pragma unroll
        for (int o = 32; o >= 1; o >>= 1) a += __shfl_xor(a, o, 64);
        acc[d] = a;   // all lanes now hold the full sum; indices compile-time (no scratch)
    }
    if (lane == 0) {
        float inv = 1.f / ls;
        float* dst = attn_out + i * E + h * DH;
        float4 o0 = { acc[0]*inv,  acc[1]*inv,  acc[2]*inv,  acc[3]*inv  };
        float4 o1 = { acc[4]*inv,  acc[5]*inv,  acc[6]*inv,  acc[7]*inv  };
        float4 o2 = { acc[8]*inv,  acc[9]*inv,  acc[10]*inv, acc[11]*inv };
        float4 o3 = { acc[12]*inv, acc[13]*inv, acc[14]*inv, acc[15]*inv };
        ((float4*)dst)[0] = o0;
        ((float4*)dst)[1] = o1;
        ((float4*)dst)[2] = o2;
        ((float4*)dst)[3] = o3;
    }
}

// ---------------- K6: fold out_proj + classifier: wf[e] = sum_t w_cls[t]*w_out[t][e]; wf[E] = bias
__global__ void fuse_kernel(const float* __restrict__ w_out, const float* __restrict__ b_out,
                            const float* __restrict__ w_cls, const float* __restrict__ b_cls,
                            float* __restrict__ wf) {
    int e = threadIdx.x;
    if (e < E) {
        float s = 0.f;
        for (int t = 0; t < E; ++t) s += w_cls[t] * w_out[t * E + e];
        wf[e] = s;
    } else if (e == E) {
        float s = 0.f;
        for (int t = 0; t < E; ++t) s += w_cls[t] * b_out[t];
        wf[E] = s + b_cls[0];
    }
}

// ---------------- K7: per-row fused-vector dot + sigmoid
__global__ __launch_bounds__(256) void final_kernel(const float* __restrict__ attn_out,
                                                    const float* __restrict__ wf,
                                                    float* __restrict__ out) {
    int tid  = blockIdx.x * blockDim.x + threadIdx.x;
    int wid  = tid >> 6;
    int lane = threadIdx.x & 63;
    if (wid >= N) return;
    const float* ar = attn_out + wid * E;
    float s = ar[lane] * wf[lane];
    if (lane < E - 64) s += ar[lane + 64] * wf[lane + 64];
    #pragma unroll
    for (int o = 32; o >= 1; o >>= 1) s += __shfl_xor(s, o, 64);
    if (lane == 0) out[wid] = 1.f / (1.f + __expf(-(s + wf[E])));
}

extern "C" void kernel_launch(void* const* d_in, const int* in_sizes, int n_in,
                              void* d_out, int out_size, void* d_ws, size_t ws_size,
                              hipStream_t stream) {
    const float* feats = (const float*)d_in[0];
    const int*   grp   = (const int*)  d_in[1];
    const float* w_in  = (const float*)d_in[2];
    const float* b_in  = (const float*)d_in[3];
    const float* w_out = (const float*)d_in[4];
    const float* b_out = (const float*)d_in[5];
    const float* w_cls = (const float*)d_in[6];
    const float* b_cls = (const float*)d_in[7];
    float* out = (float*)d_out;

    float* Qd   = (float*)d_ws;            // H*N*DH = 393216 floats
    float* Kd   = Qd + H * N * DH;
    float* Vd   = Kd + H * N * DH;
    float* attn = Vd + H * N * DH;          // N*E
    float* wf   = attn + N * E;             // 128 floats (96 + bias + pad)
    int* counts = (int*)(wf + 128);         // 64
    int* offs   = counts + 64;              // 64
    int* cursor = offs + 64;                // 64
    int* bucket = cursor + 64;              // N

    hipMemsetAsync(counts, 0, G * sizeof(int), stream);
    qkv_kernel<<<(N * QKV + 255) / 256, 256, 0, stream>>>(feats, w_in, b_in, Qd, Kd, Vd);
    hist_kernel<<<(N + 255) / 256, 256, 0, stream>>>(grp, counts);
    scan_kernel<<<1, 64, 0, stream>>>(counts, offs, cursor);
    scatter_kernel<<<(N + 255) / 256, 256, 0, stream>>>(grp, cursor, bucket);
    attn_kernel<<<(N * H * 64 + 255) / 256, 256, 0, stream>>>(Qd, Kd, Vd, grp, offs, counts, bucket, attn);
    fuse_kernel<<<1, 128, 0, stream>>>(w_out, b_out, w_cls, b_cls, wf);
    final_kernel<<<(N * 64 + 255) / 256, 256, 0, stream>>>(attn, wf, out);
}

// Round 2
// 122.918 us; speedup vs baseline: 1.6531x; 1.6531x over previous
//
#include <hip/hip_runtime.h>
#include <math.h>

#define N 4096
#define E 96
#define H 6
#define DH 16
#define G 64

typedef __attribute__((ext_vector_type(8))) short short8;   // 8 bf16 in 4 VGPRs
typedef __attribute__((ext_vector_type(4))) float f32x4;

static __device__ __forceinline__ short f2bf(float f) {
    unsigned u = __builtin_bit_cast(unsigned, f);
    unsigned r = (u + 0x7fffu + ((u >> 16) & 1u)) >> 16;    // RNE
    return (short)r;
}

// ---------------- K1: bucketing (hist+scan+scatter) + classifier fold, one block
__global__ __launch_bounds__(1024) void bucket_kernel(const int* __restrict__ grp,
                                                      int* __restrict__ counts,
                                                      int* __restrict__ offs,
                                                      int* __restrict__ perm,
                                                      const float* __restrict__ w_out,
                                                      const float* __restrict__ b_out,
                                                      const float* __restrict__ w_cls,
                                                      const float* __restrict__ b_cls,
                                                      float* __restrict__ wf) {
    __shared__ int scount[G];
    __shared__ int soff[G];
    int t = threadIdx.x;

    // classifier fold: wf[e] = sum_u w_cls[u]*w_out[u][e]; wf[E] = folded bias
    if (t >= 896) {
        int e = t - 896;
        if (e < E) {
            float s = 0.f;
            for (int u = 0; u < E; ++u) s += w_cls[u] * w_out[u * E + e];
            wf[e] = s;
        } else if (e == E) {
            float s = 0.f;
            for (int u = 0; u < E; ++u) s += w_cls[u] * b_out[u];
            wf[E] = s + b_cls[0];
        }
    }

    if (t < G) scount[t] = 0;
    __syncthreads();
    for (int i = t; i < N; i += 1024) atomicAdd(&scount[grp[i]], 1);
    __syncthreads();
    if (t == 0) {
        int run = 0;
        for (int g = 0; g < G; ++g) {
            soff[g] = run; offs[g] = run; counts[g] = scount[g]; run += scount[g];
        }
    }
    __syncthreads();
    for (int i = t; i < N; i += 1024) {
        int p = atomicAdd(&soff[grp[i]], 1);
        perm[i] = p;   // row i's slot in bucket-sorted order
    }
}

// ---------------- K2: qkv GEMM via bf16 MFMA; Q by row, K/V bucket-sorted via perm
__global__ __launch_bounds__(256) void qkv_kernel(const float* __restrict__ feats,
                                                  const float* __restrict__ w_in,
                                                  const float* __restrict__ b_in,
                                                  const int* __restrict__ perm,
                                                  float* __restrict__ Q,
                                                  float* __restrict__ Ks,
                                                  float* __restrict__ Vs) {
    int wid  = (blockIdx.x * blockDim.x + threadIdx.x) >> 6;   // 4608 waves
    int lane = threadIdx.x & 63;
    if (wid >= 256 * 18) return;
    int rt = wid / 18;            // row tile 0..255
    int ct = wid % 18;            // col tile 0..17  (part = ct/6, head = ct%6)
    int lr = lane & 15;           // A-row / B-col / D-col within tile
    int kg = lane >> 4;           // k-group 0..3

    // A fragment source: feats[rt*16+lr][kg*8 + 32*kc + j]
    const float4* fr = (const float4*)(feats + (rt * 16 + lr) * E) + kg * 2;
    // B fragment source: w_in[ct*16+lr][kg*8 + 32*kc + j]
    const float4* wr = (const float4*)(w_in + (ct * 16 + lr) * E) + kg * 2;

    f32x4 acc = {0.f, 0.f, 0.f, 0.f};
    #pragma unroll
    for (int kc = 0; kc < 3; ++kc) {
        float4 a0 = fr[kc * 8], a1 = fr[kc * 8 + 1];
        float4 b0 = wr[kc * 8], b1 = wr[kc * 8 + 1];
        short8 af, bf;
        af[0]=f2bf(a0.x); af[1]=f2bf(a0.y); af[2]=f2bf(a0.z); af[3]=f2bf(a0.w);
        af[4]=f2bf(a1.x); af[5]=f2bf(a1.y); af[6]=f2bf(a1.z); af[7]=f2bf(a1.w);
        bf[0]=f2bf(b0.x); bf[1]=f2bf(b0.y); bf[2]=f2bf(b0.z); bf[3]=f2bf(b0.w);
        bf[4]=f2bf(b1.x); bf[5]=f2bf(b1.y); bf[6]=f2bf(b1.z); bf[7]=f2bf(b1.w);
        acc = __builtin_amdgcn_mfma_f32_16x16x32_bf16(af, bf, acc, 0, 0, 0);
    }

    int col  = ct * 16 + lr;
    float bias = b_in[col];
    int part = ct / 6;
    int h    = ct % 6;
    float scale = (part == 0) ? 0.25f : 1.0f;   // 1/sqrt(DH) applied to q (post-bias)
    float* base = (part == 0) ? Q : (part == 1) ? Ks : Vs;

    #pragma unroll
    for (int r = 0; r < 4; ++r) {
        int row = rt * 16 + kg * 4 + r;
        float v = (acc[r] + bias) * scale;
        int pos = (part == 0) ? row : perm[row];
        base[(h * N + pos) * DH + lr] = v;
    }
}

// ---------------- K3: attention; wave per (row, head); K/V reads coalesced
__global__ __launch_bounds__(256) void attn_kernel(const float* __restrict__ Q,
                                                   const float* __restrict__ Ks,
                                                   const float* __restrict__ Vs,
                                                   const int* __restrict__ grp,
                                                   const int* __restrict__ offs,
                                                   const int* __restrict__ counts,
                                                   float* __restrict__ attn_out) {
    int wid  = (blockIdx.x * blockDim.x + threadIdx.x) >> 6;
    int lane = threadIdx.x & 63;
    if (wid >= N * H) return;
    int i = wid & (N - 1);
    int h = wid >> 12;
    int g = grp[i];
    int off = offs[g], cnt = counts[g];

    const float4* qp = (const float4*)(Q + (h * N + i) * DH);
    float4 q0 = qp[0], q1 = qp[1], q2 = qp[2], q3 = qp[3];

    float m = -INFINITY, l = 0.f;
    float acc[DH];
    #pragma unroll
    for (int d = 0; d < DH; ++d) acc[d] = 0.f;

    for (int mm = lane; mm < cnt; mm += 64) {
        const float4* kp = (const float4*)(Ks + (h * N + off + mm) * DH);
        float4 k0 = kp[0], k1 = kp[1], k2 = kp[2], k3 = kp[3];
        float s = q0.x*k0.x + q0.y*k0.y + q0.z*k0.z + q0.w*k0.w
                + q1.x*k1.x + q1.y*k1.y + q1.z*k1.z + q1.w*k1.w
                + q2.x*k2.x + q2.y*k2.y + q2.z*k2.z + q2.w*k2.w
                + q3.x*k3.x + q3.y*k3.y + q3.z*k3.z + q3.w*k3.w;
        float nm = fmaxf(m, s);
        float c = __expf(m - nm);
        float p = __expf(s - nm);
        l = l * c + p;
        const float4* vp = (const float4*)(Vs + (h * N + off + mm) * DH);
        float4 v0 = vp[0], v1 = vp[1], v2 = vp[2], v3 = vp[3];
        acc[0]=acc[0]*c+p*v0.x;  acc[1]=acc[1]*c+p*v0.y;  acc[2]=acc[2]*c+p*v0.z;  acc[3]=acc[3]*c+p*v0.w;
        acc[4]=acc[4]*c+p*v1.x;  acc[5]=acc[5]*c+p*v1.y;  acc[6]=acc[6]*c+p*v1.z;  acc[7]=acc[7]*c+p*v1.w;
        acc[8]=acc[8]*c+p*v2.x;  acc[9]=acc[9]*c+p*v2.y;  acc[10]=acc[10]*c+p*v2.z; acc[11]=acc[11]*c+p*v2.w;
        acc[12]=acc[12]*c+p*v3.x; acc[13]=acc[13]*c+p*v3.y; acc[14]=acc[14]*c+p*v3.z; acc[15]=acc[15]*c+p*v3.w;
        m = nm;
    }

    // 64-lane online-softmax combine
    float M = m;
    #pragma unroll
    for (int o = 32; o >= 1; o >>= 1) M = fmaxf(M, __shfl_xor(M, o, 64));
    float scale = (m == -INFINITY) ? 0.f : __expf(m - M);
    float ls = l * scale;
    #pragma unroll
    for (int o = 32; o >= 1; o >>= 1) ls += __shfl_xor(ls, o, 64);
    #pragma unroll
    for (int d = 0; d < DH; ++d) {
        float a = acc[d] * scale;
        #pragma unroll
        for (int o = 32; o >= 1; o >>= 1) a += __shfl_xor(a, o, 64);
        acc[d] = a;
    }
    if (lane == 0) {
        float inv = 1.f / ls;
        float* dst = attn_out + i * E + h * DH;
        float4 o0 = { acc[0]*inv,  acc[1]*inv,  acc[2]*inv,  acc[3]*inv  };
        float4 o1 = { acc[4]*inv,  acc[5]*inv,  acc[6]*inv,  acc[7]*inv  };
        float4 o2 = { acc[8]*inv,  acc[9]*inv,  acc[10]*inv, acc[11]*inv };
        float4 o3 = { acc[12]*inv, acc[13]*inv, acc[14]*inv, acc[15]*inv };
        ((float4*)dst)[0] = o0; ((float4*)dst)[1] = o1;
        ((float4*)dst)[2] = o2; ((float4*)dst)[3] = o3;
    }
}

// ---------------- K4: per-row dot with folded classifier + sigmoid
__global__ __launch_bounds__(256) void final_kernel(const float* __restrict__ attn_out,
                                                    const float* __restrict__ wf,
                                                    float* __restrict__ out) {
    int wid  = (blockIdx.x * blockDim.x + threadIdx.x) >> 6;
    int lane = threadIdx.x & 63;
    if (wid >= N) return;
    const float* ar = attn_out + wid * E;
    float s = ar[lane] * wf[lane];
    if (lane < E - 64) s += ar[lane + 64] * wf[lane + 64];
    #pragma unroll
    for (int o = 32; o >= 1; o >>= 1) s += __shfl_xor(s, o, 64);
    if (lane == 0) out[wid] = 1.f / (1.f + __expf(-(s + wf[E])));
}

extern "C" void kernel_launch(void* const* d_in, const int* in_sizes, int n_in,
                              void* d_out, int out_size, void* d_ws, size_t ws_size,
                              hipStream_t stream) {
    const float* feats = (const float*)d_in[0];
    const int*   grp   = (const int*)  d_in[1];
    const float* w_in  = (const float*)d_in[2];
    const float* b_in  = (const float*)d_in[3];
    const float* w_out = (const float*)d_in[4];
    const float* b_out = (const float*)d_in[5];
    const float* w_cls = (const float*)d_in[6];
    const float* b_cls = (const float*)d_in[7];
    float* out = (float*)d_out;

    float* Q    = (float*)d_ws;             // H*N*DH
    float* Ks   = Q  + H * N * DH;          // bucket-sorted
    float* Vs   = Ks + H * N * DH;          // bucket-sorted
    float* attn = Vs + H * N * DH;          // N*E
    float* wf   = attn + N * E;             // 128 (96 + folded bias + pad)
    int* counts = (int*)(wf + 128);         // 64
    int* offs   = counts + 64;              // 64
    int* perm   = offs + 64;                // N

    bucket_kernel<<<1, 1024, 0, stream>>>(grp, counts, offs, perm,
                                          w_out, b_out, w_cls, b_cls, wf);
    qkv_kernel<<<(256 * 18 * 64) / 256, 256, 0, stream>>>(feats, w_in, b_in, perm, Q, Ks, Vs);
    attn_kernel<<<(N * H * 64) / 256, 256, 0, stream>>>(Q, Ks, Vs, grp, offs, counts, attn);
    final_kernel<<<(N * 64) / 256, 256, 0, stream>>>(attn, wf, out);
}